// Round 1
// baseline (771.532 us; speedup 1.0000x reference)
//
#include <hip/hip_runtime.h>

#define HIDDEN 128
#define NRAD 6

__device__ __forceinline__ float swishf(float z) {
    return z / (1.0f + __expf(-z));
}

// ---------------------------------------------------------------------------
// Kernel 1: T1 = emb_table @ W1, T3 = emb_table @ W3  (95x128 each, tiny)
// Also writes the trailing scalar output "1".
// ---------------------------------------------------------------------------
__global__ void k_emb_proj(const float* __restrict__ emb, const float* __restrict__ W,
                           float* __restrict__ T1, float* __restrict__ T3,
                           float* __restrict__ out_scalar) {
    int v = blockIdx.x;
    int h = threadIdx.x;
    if (v == 0 && h == 0) *out_scalar = 1.0f;
    const float* er = emb + v * HIDDEN;
    float a1 = 0.f, a3 = 0.f;
    #pragma unroll 4
    for (int k = 0; k < HIDDEN; ++k) {
        float e = er[k];
        a1 += e * W[k * HIDDEN + h];             // W1 rows [0,128)
        a3 += e * W[(256 + k) * HIDDEN + h];     // W3 rows [256,384)
    }
    T1[v * HIDDEN + h] = a1;
    T3[v * HIDDEN + h] = a3;
}

// ---------------------------------------------------------------------------
// Kernel 2: per-node A[n] = T1[x[n]] + chi[n]@W2 ; B[n] = T3[x[n]] + chi[n]@W4
// 32 nodes per block, 256 threads. Thread = (node-group eg 0..3, h-pair hg 0..63)
// ---------------------------------------------------------------------------
#define NB 32
__global__ __launch_bounds__(256) void k_node(const int* __restrict__ x,
        const float* __restrict__ chi, const float* __restrict__ W,
        const float* __restrict__ T1, const float* __restrict__ T3,
        float* __restrict__ A, float* __restrict__ B, int n_nodes) {
    __shared__ float chi_s[NB][HIDDEN];   // 16 KB
    __shared__ int x_s[NB];
    int n0 = blockIdx.x * NB;
    int t = threadIdx.x;
    {
        const float4* src = (const float4*)(chi + (size_t)n0 * HIDDEN);
        float4* dst = (float4*)(&chi_s[0][0]);
        #pragma unroll
        for (int q = t; q < NB * HIDDEN / 4; q += 256) dst[q] = src[q];
        if (t < NB) x_s[t] = x[n0 + t];
    }
    __syncthreads();

    int hg = t & 63;        // h pair
    int eg = t >> 6;        // node group (wave id): nodes eg*8 .. eg*8+7
    int h0 = hg * 2;
    const float* W2 = W + 128 * HIDDEN;
    const float* W4 = W + 384 * HIDDEN;
    float accA[8][2] = {};
    float accB[8][2] = {};
    for (int k = 0; k < HIDDEN; k += 2) {
        float2 w2a = *(const float2*)(W2 + k * HIDDEN + h0);
        float2 w2b = *(const float2*)(W2 + (k + 1) * HIDDEN + h0);
        float2 w4a = *(const float2*)(W4 + k * HIDDEN + h0);
        float2 w4b = *(const float2*)(W4 + (k + 1) * HIDDEN + h0);
        #pragma unroll
        for (int m = 0; m < 8; ++m) {
            int n = eg * 8 + m;
            float2 c = *(const float2*)(&chi_s[n][k]);   // wave-uniform: broadcast
            accA[m][0] += c.x * w2a.x + c.y * w2b.x;
            accA[m][1] += c.x * w2a.y + c.y * w2b.y;
            accB[m][0] += c.x * w4a.x + c.y * w4b.x;
            accB[m][1] += c.x * w4a.y + c.y * w4b.y;
        }
    }
    #pragma unroll
    for (int m = 0; m < 8; ++m) {
        int n = eg * 8 + m;
        int gn = n0 + n;
        if (gn < n_nodes) {
            int xv = x_s[n];
            float2 t1 = *(const float2*)(T1 + xv * HIDDEN + h0);
            float2 t3 = *(const float2*)(T3 + xv * HIDDEN + h0);
            *(float2*)(A + (size_t)gn * HIDDEN + h0) = make_float2(accA[m][0] + t1.x, accA[m][1] + t1.y);
            *(float2*)(B + (size_t)gn * HIDDEN + h0) = make_float2(accB[m][0] + t3.x, accB[m][1] + t3.y);
        }
    }
}

// ---------------------------------------------------------------------------
// Kernel 3: per-edge  out[e] = swish(A[i[e]] + B[j[e]] + swish(rbf@W_rbf+b_rbf)@W5 + b)
// 64 edges per block, 256 threads. Wave eg owns 16 edges; lane hg owns h-pair.
// ---------------------------------------------------------------------------
#define EB 64
__global__ __launch_bounds__(256) void k_edge(const float* __restrict__ rbf,
        const int* __restrict__ ei, const int* __restrict__ ej,
        const float* __restrict__ W_rbf, const float* __restrict__ b_rbf,
        const float* __restrict__ W, const float* __restrict__ b,
        const float* __restrict__ A, const float* __restrict__ B,
        float* __restrict__ out, int n_edges) {
    __shared__ float rbf0_s[EB][HIDDEN];   // 32 KB
    __shared__ float rbf_s[EB][NRAD];
    __shared__ int i_s[EB], j_s[EB];
    int e0 = blockIdx.x * EB;
    int t = threadIdx.x;

    for (int q = t; q < EB * NRAD; q += 256) {
        int ge = e0 + q / NRAD;
        rbf_s[q / NRAD][q % NRAD] = (ge < n_edges) ? rbf[(size_t)e0 * NRAD + q] : 0.f;
    }
    if (t < EB) {
        int ge = e0 + t;
        i_s[t] = (ge < n_edges) ? ei[ge] : 0;
        j_s[t] = (ge < n_edges) ? ej[ge] : 0;
    }
    __syncthreads();

    // phase 1: rbf0 = swish(rbf @ W_rbf + b_rbf) into LDS
    {
        int h = t & 127;
        int g = t >> 7;   // 0..1
        float wr[NRAD];
        #pragma unroll
        for (int r = 0; r < NRAD; ++r) wr[r] = W_rbf[r * HIDDEN + h];
        float bb = b_rbf[h];
        #pragma unroll 4
        for (int m = 0; m < EB / 2; ++m) {
            int e = g * (EB / 2) + m;
            float z = bb;
            #pragma unroll
            for (int r = 0; r < NRAD; ++r) z += rbf_s[e][r] * wr[r];
            rbf0_s[e][h] = swishf(z);
        }
    }
    __syncthreads();

    // phase 2: r5 = rbf0 @ W5, add gathers, swish, store
    int hg = t & 63;
    int eg = t >> 6;       // wave id, edges eg*16..eg*16+15
    int h0 = hg * 2;
    const float* W5 = W + 512 * HIDDEN;
    float acc[16][2] = {};
    for (int k = 0; k < HIDDEN; k += 2) {
        float2 w5a = *(const float2*)(W5 + k * HIDDEN + h0);
        float2 w5b = *(const float2*)(W5 + (k + 1) * HIDDEN + h0);
        #pragma unroll
        for (int m = 0; m < 16; ++m) {
            float2 p = *(const float2*)(&rbf0_s[eg * 16 + m][k]);  // broadcast
            acc[m][0] += p.x * w5a.x + p.y * w5b.x;
            acc[m][1] += p.x * w5a.y + p.y * w5b.y;
        }
    }
    float2 bb2 = *(const float2*)(b + h0);
    #pragma unroll
    for (int m = 0; m < 16; ++m) {
        int e = eg * 16 + m;
        int ge = e0 + e;
        if (ge < n_edges) {
            float2 av = *(const float2*)(A + (size_t)i_s[e] * HIDDEN + h0);
            float2 bv = *(const float2*)(B + (size_t)j_s[e] * HIDDEN + h0);
            float z0 = acc[m][0] + av.x + bv.x + bb2.x;
            float z1 = acc[m][1] + av.y + bv.y + bb2.y;
            *(float2*)(out + (size_t)ge * HIDDEN + h0) = make_float2(swishf(z0), swishf(z1));
        }
    }
}

extern "C" void kernel_launch(void* const* d_in, const int* in_sizes, int n_in,
                              void* d_out, int out_size, void* d_ws, size_t ws_size,
                              hipStream_t stream) {
    const int*   x     = (const int*)d_in[0];
    const float* chi   = (const float*)d_in[1];
    const float* rbf   = (const float*)d_in[2];
    const int*   ei    = (const int*)d_in[3];
    const int*   ej    = (const int*)d_in[4];
    const float* emb   = (const float*)d_in[5];
    const float* W_rbf = (const float*)d_in[6];
    const float* b_rbf = (const float*)d_in[7];
    const float* W     = (const float*)d_in[8];
    const float* bvec  = (const float*)d_in[9];
    float* out = (float*)d_out;

    int n_nodes = in_sizes[0];
    int n_edges = in_sizes[3];
    int vocab   = in_sizes[5] / HIDDEN;

    float* A  = (float*)d_ws;
    float* B  = A + (size_t)n_nodes * HIDDEN;
    float* T1 = B + (size_t)n_nodes * HIDDEN;
    float* T3 = T1 + (size_t)vocab * HIDDEN;

    k_emb_proj<<<vocab, HIDDEN, 0, stream>>>(emb, W, T1, T3, out + (out_size - 1));
    k_node<<<(n_nodes + NB - 1) / NB, 256, 0, stream>>>(x, chi, W, T1, T3, A, B, n_nodes);
    k_edge<<<(n_edges + EB - 1) / EB, 256, 0, stream>>>(rbf, ei, ej, W_rbf, b_rbf, W, bvec,
                                                        A, B, out, n_edges);
}

// Round 2
// 462.810 us; speedup vs baseline: 1.6671x; 1.6671x over previous
//
#include <hip/hip_runtime.h>

#define HIDDEN 128
#define NRAD 6

typedef short bf16x8 __attribute__((ext_vector_type(8)));
typedef float f32x4 __attribute__((ext_vector_type(4)));

__device__ __forceinline__ float swishf(float z) {
    return z / (1.0f + __expf(-z));
}

__device__ __forceinline__ unsigned short f2bf(float f) {
    unsigned int u = __float_as_uint(f);
    unsigned int r = (u + 0x7FFFu + ((u >> 16) & 1u)) >> 16;
    return (unsigned short)r;
}

// ---------------------------------------------------------------------------
// Kernel 1: T1 = emb_table @ W1, T3 = emb_table @ W3  (95x128 each, tiny)
// Also writes the trailing scalar output "1".
// ---------------------------------------------------------------------------
__global__ void k_emb_proj(const float* __restrict__ emb, const float* __restrict__ W,
                           float* __restrict__ T1, float* __restrict__ T3,
                           float* __restrict__ out_scalar) {
    int v = blockIdx.x;
    int h = threadIdx.x;
    if (v == 0 && h == 0) *out_scalar = 1.0f;
    const float* er = emb + v * HIDDEN;
    float a1 = 0.f, a3 = 0.f;
    #pragma unroll 4
    for (int k = 0; k < HIDDEN; ++k) {
        float e = er[k];
        a1 += e * W[k * HIDDEN + h];             // W1 rows [0,128)
        a3 += e * W[(256 + k) * HIDDEN + h];     // W3 rows [256,384)
    }
    T1[v * HIDDEN + h] = a1;
    T3[v * HIDDEN + h] = a3;
}

// ---------------------------------------------------------------------------
// Kernel 1b: repack W5 (f32 row-major) into bf16 MFMA B-fragments.
// Fragment order: tile = n*4+kt (n = col-tile 0..7, kt = k-tile 0..3),
// lane l holds B[k = kt*32 + (l>>4)*8 + j][col = n*16 + (l&15)], j=0..7.
// w5f[((n*4+kt)*64 + l)*8 + j]
// ---------------------------------------------------------------------------
__global__ void k_w5prep(const float* __restrict__ W, short* __restrict__ w5f) {
    int t = blockIdx.x * 256 + threadIdx.x;   // 0..2047
    int l = t & 63;
    int tile = t >> 6;                         // 0..31
    int n = tile >> 2, kt = tile & 3;
    int k0 = kt * 32 + (l >> 4) * 8;
    int col = n * 16 + (l & 15);
    const float* W5 = W + 512 * HIDDEN;
    bf16x8 v;
    #pragma unroll
    for (int j = 0; j < 8; ++j) v[j] = (short)f2bf(W5[(k0 + j) * HIDDEN + col]);
    *(bf16x8*)(w5f + (size_t)t * 8) = v;
}

// ---------------------------------------------------------------------------
// Kernel 2: per-node A[n] = T1[x[n]] + chi[n]@W2 ; B[n] = T3[x[n]] + chi[n]@W4
// ---------------------------------------------------------------------------
#define NB 32
__global__ __launch_bounds__(256) void k_node(const int* __restrict__ x,
        const float* __restrict__ chi, const float* __restrict__ W,
        const float* __restrict__ T1, const float* __restrict__ T3,
        float* __restrict__ A, float* __restrict__ B, int n_nodes) {
    __shared__ float chi_s[NB][HIDDEN];   // 16 KB
    __shared__ int x_s[NB];
    int n0 = blockIdx.x * NB;
    int t = threadIdx.x;
    {
        const float4* src = (const float4*)(chi + (size_t)n0 * HIDDEN);
        float4* dst = (float4*)(&chi_s[0][0]);
        #pragma unroll
        for (int q = t; q < NB * HIDDEN / 4; q += 256) dst[q] = src[q];
        if (t < NB) x_s[t] = x[n0 + t];
    }
    __syncthreads();

    int hg = t & 63;
    int eg = t >> 6;
    int h0 = hg * 2;
    const float* W2 = W + 128 * HIDDEN;
    const float* W4 = W + 384 * HIDDEN;
    float accA[8][2] = {};
    float accB[8][2] = {};
    for (int k = 0; k < HIDDEN; k += 2) {
        float2 w2a = *(const float2*)(W2 + k * HIDDEN + h0);
        float2 w2b = *(const float2*)(W2 + (k + 1) * HIDDEN + h0);
        float2 w4a = *(const float2*)(W4 + k * HIDDEN + h0);
        float2 w4b = *(const float2*)(W4 + (k + 1) * HIDDEN + h0);
        #pragma unroll
        for (int m = 0; m < 8; ++m) {
            int n = eg * 8 + m;
            float2 c = *(const float2*)(&chi_s[n][k]);   // wave-uniform broadcast
            accA[m][0] += c.x * w2a.x + c.y * w2b.x;
            accA[m][1] += c.x * w2a.y + c.y * w2b.y;
            accB[m][0] += c.x * w4a.x + c.y * w4b.x;
            accB[m][1] += c.x * w4a.y + c.y * w4b.y;
        }
    }
    #pragma unroll
    for (int m = 0; m < 8; ++m) {
        int n = eg * 8 + m;
        int gn = n0 + n;
        if (gn < n_nodes) {
            int xv = x_s[n];
            float2 t1 = *(const float2*)(T1 + xv * HIDDEN + h0);
            float2 t3 = *(const float2*)(T3 + xv * HIDDEN + h0);
            *(float2*)(A + (size_t)gn * HIDDEN + h0) = make_float2(accA[m][0] + t1.x, accA[m][1] + t1.y);
            *(float2*)(B + (size_t)gn * HIDDEN + h0) = make_float2(accB[m][0] + t3.x, accB[m][1] + t3.y);
        }
    }
}

// ---------------------------------------------------------------------------
// Kernel 3 (MFMA): out[e] = swish(A[i] + B[j] + swish(rbf@W_rbf+b_rbf)@W5 + b)
// 64 edges/block, 4 waves; wave owns 16 edges. P (rbf0) staged as bf16 in
// XOR-swizzled LDS; W5 B-fragments streamed from precomputed w5f (L1-hot).
// ---------------------------------------------------------------------------
#define EB 64
__global__ __launch_bounds__(256) void k_edge(const float* __restrict__ rbf,
        const int* __restrict__ ei, const int* __restrict__ ej,
        const float* __restrict__ W_rbf, const float* __restrict__ b_rbf,
        const float* __restrict__ b,
        const short* __restrict__ w5f,
        const float* __restrict__ A, const float* __restrict__ B,
        float* __restrict__ out, int n_edges) {
    __shared__ unsigned short p_s[EB * HIDDEN];   // 16 KB bf16, row-swizzled
    __shared__ float rbf_s[EB][NRAD];
    __shared__ int i_s[EB], j_s[EB];
    int e0 = blockIdx.x * EB;
    int t = threadIdx.x;
    int l = t & 63;
    int wv = t >> 6;

    for (int q = t; q < EB * NRAD; q += 256) {
        int g = e0 * NRAD + q;
        ((float*)rbf_s)[q] = (g < n_edges * NRAD) ? rbf[g] : 0.f;
    }
    if (t < EB) {
        int ge = e0 + t;
        i_s[t] = (ge < n_edges) ? ei[ge] : 0;
        j_s[t] = (ge < n_edges) ? ej[ge] : 0;
    }
    __syncthreads();

    // phase 1: p = swish(rbf @ W_rbf + b_rbf) -> bf16 into swizzled LDS
    {
        int h0 = l * 2;
        float2 wr[NRAD];
        #pragma unroll
        for (int r = 0; r < NRAD; ++r) wr[r] = *(const float2*)(W_rbf + r * HIDDEN + h0);
        float2 bb = *(const float2*)(b_rbf + h0);
        #pragma unroll
        for (int m = 0; m < 16; ++m) {
            int e = wv + 4 * m;                  // wave-uniform row -> LDS broadcast
            float zx = bb.x, zy = bb.y;
            #pragma unroll
            for (int r = 0; r < NRAD; ++r) {
                float rv = rbf_s[e][r];
                zx += rv * wr[r].x;
                zy += rv * wr[r].y;
            }
            unsigned int pk = (unsigned int)f2bf(swishf(zx)) |
                              ((unsigned int)f2bf(swishf(zy)) << 16);
            unsigned int byte = (unsigned int)(e * 256 + h0 * 2) ^ ((e & 7) << 4);
            *(unsigned int*)((char*)p_s + byte) = pk;
        }
    }
    __syncthreads();

    // phase 2: A-fragments from LDS (swizzled ds_read_b128)
    bf16x8 afrag[4];
    {
        int rloc = wv * 16 + (l & 15);
        unsigned int base = (unsigned int)(rloc * 256 + (l >> 4) * 16);
        unsigned int swz = (unsigned int)((rloc & 7) << 4);
        #pragma unroll
        for (int kt = 0; kt < 4; ++kt)
            afrag[kt] = *(const bf16x8*)((const char*)p_s + ((base + kt * 64) ^ swz));
    }

    int ia[4], ja[4];
    #pragma unroll
    for (int r = 0; r < 4; ++r) {
        int eloc = wv * 16 + (l >> 4) * 4 + r;
        ia[r] = i_s[eloc];
        ja[r] = j_s[eloc];
    }

    #pragma unroll
    for (int n = 0; n < 8; ++n) {
        f32x4 acc = {0.f, 0.f, 0.f, 0.f};
        #pragma unroll
        for (int kt = 0; kt < 4; ++kt) {
            bf16x8 bfrag = *(const bf16x8*)(w5f + ((size_t)(n * 4 + kt) * 64 + l) * 8);
            acc = __builtin_amdgcn_mfma_f32_16x16x32_bf16(afrag[kt], bfrag, acc, 0, 0, 0);
        }
        int h = n * 16 + (l & 15);
        float bb = b[h];
        #pragma unroll
        for (int r = 0; r < 4; ++r) {
            int eloc = wv * 16 + (l >> 4) * 4 + r;
            int ge = e0 + eloc;
            if (ge < n_edges) {
                float av = A[(size_t)ia[r] * HIDDEN + h];
                float bv = B[(size_t)ja[r] * HIDDEN + h];
                out[(size_t)ge * HIDDEN + h] = swishf(acc[r] + av + bv + bb);
            }
        }
    }
}

extern "C" void kernel_launch(void* const* d_in, const int* in_sizes, int n_in,
                              void* d_out, int out_size, void* d_ws, size_t ws_size,
                              hipStream_t stream) {
    const int*   x     = (const int*)d_in[0];
    const float* chi   = (const float*)d_in[1];
    const float* rbf   = (const float*)d_in[2];
    const int*   ei    = (const int*)d_in[3];
    const int*   ej    = (const int*)d_in[4];
    const float* emb   = (const float*)d_in[5];
    const float* W_rbf = (const float*)d_in[6];
    const float* b_rbf = (const float*)d_in[7];
    const float* W     = (const float*)d_in[8];
    const float* bvec  = (const float*)d_in[9];
    float* out = (float*)d_out;

    int n_nodes = in_sizes[0];
    int n_edges = in_sizes[3];
    int vocab   = in_sizes[5] / HIDDEN;

    float* A  = (float*)d_ws;
    float* B  = A + (size_t)n_nodes * HIDDEN;
    float* T1 = B + (size_t)n_nodes * HIDDEN;
    float* T3 = T1 + (size_t)vocab * HIDDEN;
    short* w5f = (short*)(T3 + (size_t)vocab * HIDDEN);   // 32 KB of bf16 fragments

    k_emb_proj<<<vocab, HIDDEN, 0, stream>>>(emb, W, T1, T3, out + (out_size - 1));
    k_w5prep<<<8, 256, 0, stream>>>(W, w5f);
    k_node<<<(n_nodes + NB - 1) / NB, 256, 0, stream>>>(x, chi, W, T1, T3, A, B, n_nodes);
    k_edge<<<(n_edges + EB - 1) / EB, 256, 0, stream>>>(rbf, ei, ej, W_rbf, b_rbf, bvec,
                                                        w5f, A, B, out, n_edges);
}

// Round 3
// 359.087 us; speedup vs baseline: 2.1486x; 1.2889x over previous
//
#include <hip/hip_runtime.h>

#define HIDDEN 128
#define NRAD 6

typedef short bf16x8 __attribute__((ext_vector_type(8)));
typedef short bf16x4 __attribute__((ext_vector_type(4)));
typedef float f32x4 __attribute__((ext_vector_type(4)));

__device__ __forceinline__ float swishf(float z) {
    return z / (1.0f + __expf(-z));
}

__device__ __forceinline__ unsigned short f2bf(float f) {
    unsigned int u = __float_as_uint(f);
    unsigned int r = (u + 0x7FFFu + ((u >> 16) & 1u)) >> 16;
    return (unsigned short)r;
}

__device__ __forceinline__ float bf2f(unsigned short s) {
    return __uint_as_float(((unsigned int)s) << 16);
}

// ---------------------------------------------------------------------------
// Kernel 1: T1 = emb_table @ W1, T3 = emb_table @ W3  (95x128 each, tiny)
// Also writes the trailing scalar output "1".
// ---------------------------------------------------------------------------
__global__ void k_emb_proj(const float* __restrict__ emb, const float* __restrict__ W,
                           float* __restrict__ T1, float* __restrict__ T3,
                           float* __restrict__ out_scalar) {
    int v = blockIdx.x;
    int h = threadIdx.x;
    if (v == 0 && h == 0) *out_scalar = 1.0f;
    const float* er = emb + v * HIDDEN;
    float a1 = 0.f, a3 = 0.f;
    #pragma unroll 4
    for (int k = 0; k < HIDDEN; ++k) {
        float e = er[k];
        a1 += e * W[k * HIDDEN + h];             // W1 rows [0,128)
        a3 += e * W[(256 + k) * HIDDEN + h];     // W3 rows [256,384)
    }
    T1[v * HIDDEN + h] = a1;
    T3[v * HIDDEN + h] = a3;
}

// ---------------------------------------------------------------------------
// Kernel 1b: repack W2, W4, W5 (f32 row-major) into bf16 MFMA "A-operand"
// fragments of W^T: tile = n*4+kt, lane l holds W[k = kt*32+(l>>4)*8+j][col =
// n*16+(l&15)].  wf[m][((n*4+kt)*64 + l)*8 + j], m in {0:W2, 1:W4, 2:W5}.
// ---------------------------------------------------------------------------
__global__ void k_wprep(const float* __restrict__ W, short* __restrict__ wf) {
    int gid = blockIdx.x * 256 + threadIdx.x;   // 0..6143
    int m = gid >> 11;                           // 0..2
    int t = gid & 2047;
    int l = t & 63;
    int tile = t >> 6;                           // 0..31
    int n = tile >> 2, kt = tile & 3;
    int k0 = kt * 32 + (l >> 4) * 8;
    int col = n * 16 + (l & 15);
    static const int rowoff[3] = {128, 384, 512};   // W2, W4, W5
    const float* Wm = W + rowoff[m] * HIDDEN;
    bf16x8 v;
    #pragma unroll
    for (int j = 0; j < 8; ++j) v[j] = (short)f2bf(Wm[(k0 + j) * HIDDEN + col]);
    *(bf16x8*)(wf + (size_t)gid * 8) = v;
}

// ---------------------------------------------------------------------------
// Kernel 2 (MFMA): per-node A[n] = T1[x[n]] + chi[n]@W2 ; B[n] = T3[x[n]] + chi[n]@W4
// 64 nodes/block, 4 waves; wave owns 16 nodes. chi staged bf16 in swizzled LDS.
// Swapped-operand MFMA: D[h][node]; lane = (node l&15, h-quad (l>>4)*4).
// Outputs stored as bf16.
// ---------------------------------------------------------------------------
#define NB 64
__global__ __launch_bounds__(256) void k_node(const int* __restrict__ x,
        const float* __restrict__ chi,
        const short* __restrict__ w2f, const short* __restrict__ w4f,
        const float* __restrict__ T1, const float* __restrict__ T3,
        short* __restrict__ Abf, short* __restrict__ Bbf, int n_nodes) {
    __shared__ unsigned short chi_s[NB * HIDDEN];   // 16 KB bf16, row-swizzled
    __shared__ int x_s[NB];
    int n0 = blockIdx.x * NB;
    int t = threadIdx.x;
    int l = t & 63;
    int wv = t >> 6;

    #pragma unroll
    for (int it = 0; it < 8; ++it) {
        int q = t + it * 256;            // float4 segment id, 0..2047
        int row = q >> 5, s = q & 31;
        int gn = n0 + row;
        float4 c = (gn < n_nodes) ? *(const float4*)(chi + (size_t)gn * HIDDEN + s * 4)
                                  : make_float4(0.f, 0.f, 0.f, 0.f);
        bf16x4 v;
        v[0] = (short)f2bf(c.x); v[1] = (short)f2bf(c.y);
        v[2] = (short)f2bf(c.z); v[3] = (short)f2bf(c.w);
        unsigned int byte = (unsigned int)(row * 256 + s * 8) ^ ((row & 7) << 4);
        *(bf16x4*)((char*)chi_s + byte) = v;
    }
    if (t < NB) {
        int gn = n0 + t;
        x_s[t] = (gn < n_nodes) ? x[gn] : 0;
    }
    __syncthreads();

    bf16x8 cfrag[4];
    {
        int rloc = wv * 16 + (l & 15);
        unsigned int base = (unsigned int)(rloc * 256 + (l >> 4) * 16);
        unsigned int swz = (unsigned int)((rloc & 7) << 4);
        #pragma unroll
        for (int kt = 0; kt < 4; ++kt)
            cfrag[kt] = *(const bf16x8*)((const char*)chi_s + ((base + kt * 64) ^ swz));
    }

    int nd_loc = wv * 16 + (l & 15);
    int gn = n0 + nd_loc;
    int xv = x_s[nd_loc];
    int hq = (l >> 4) * 4;

    #pragma unroll
    for (int n = 0; n < 8; ++n) {
        f32x4 aA = {0.f, 0.f, 0.f, 0.f};
        f32x4 aB = {0.f, 0.f, 0.f, 0.f};
        #pragma unroll
        for (int kt = 0; kt < 4; ++kt) {
            bf16x8 w2 = *(const bf16x8*)(w2f + ((size_t)(n * 4 + kt) * 64 + l) * 8);
            bf16x8 w4 = *(const bf16x8*)(w4f + ((size_t)(n * 4 + kt) * 64 + l) * 8);
            aA = __builtin_amdgcn_mfma_f32_16x16x32_bf16(w2, cfrag[kt], aA, 0, 0, 0);
            aB = __builtin_amdgcn_mfma_f32_16x16x32_bf16(w4, cfrag[kt], aB, 0, 0, 0);
        }
        if (gn < n_nodes) {
            int h = n * 16 + hq;
            float4 t1 = *(const float4*)(T1 + (size_t)xv * HIDDEN + h);
            float4 t3 = *(const float4*)(T3 + (size_t)xv * HIDDEN + h);
            bf16x4 oa, ob;
            oa[0] = (short)f2bf(aA[0] + t1.x); oa[1] = (short)f2bf(aA[1] + t1.y);
            oa[2] = (short)f2bf(aA[2] + t1.z); oa[3] = (short)f2bf(aA[3] + t1.w);
            ob[0] = (short)f2bf(aB[0] + t3.x); ob[1] = (short)f2bf(aB[1] + t3.y);
            ob[2] = (short)f2bf(aB[2] + t3.z); ob[3] = (short)f2bf(aB[3] + t3.w);
            *(bf16x4*)(Abf + (size_t)gn * HIDDEN + h) = oa;
            *(bf16x4*)(Bbf + (size_t)gn * HIDDEN + h) = ob;
        }
    }
}

// ---------------------------------------------------------------------------
// Kernel 3 (MFMA): out[e] = swish(A[i] + B[j] + swish(rbf@W_rbf+b_rbf)@W5 + b)
// 64 edges/block, 4 waves. Swapped operands: D[h][edge] -> float4 epilogue.
// ---------------------------------------------------------------------------
#define EB 64
__global__ __launch_bounds__(256) void k_edge(const float* __restrict__ rbf,
        const int* __restrict__ ei, const int* __restrict__ ej,
        const float* __restrict__ W_rbf, const float* __restrict__ b_rbf,
        const float* __restrict__ b,
        const short* __restrict__ w5f,
        const short* __restrict__ Abf, const short* __restrict__ Bbf,
        float* __restrict__ out, int n_edges) {
    __shared__ unsigned short p_s[EB * HIDDEN];   // 16 KB bf16, row-swizzled
    __shared__ float rbf_s[EB][NRAD];
    __shared__ int i_s[EB], j_s[EB];
    int e0 = blockIdx.x * EB;
    int t = threadIdx.x;
    int l = t & 63;
    int wv = t >> 6;

    for (int q = t; q < EB * NRAD; q += 256) {
        int g = e0 * NRAD + q;
        ((float*)rbf_s)[q] = (g < n_edges * NRAD) ? rbf[g] : 0.f;
    }
    if (t < EB) {
        int ge = e0 + t;
        i_s[t] = (ge < n_edges) ? ei[ge] : 0;
        j_s[t] = (ge < n_edges) ? ej[ge] : 0;
    }
    __syncthreads();

    // phase 1: p = swish(rbf @ W_rbf + b_rbf) -> bf16 into swizzled LDS
    {
        int h0 = l * 2;
        float2 wr[NRAD];
        #pragma unroll
        for (int r = 0; r < NRAD; ++r) wr[r] = *(const float2*)(W_rbf + r * HIDDEN + h0);
        float2 bb = *(const float2*)(b_rbf + h0);
        #pragma unroll
        for (int m = 0; m < 16; ++m) {
            int e = wv + 4 * m;                  // wave-uniform row -> LDS broadcast
            float zx = bb.x, zy = bb.y;
            #pragma unroll
            for (int r = 0; r < NRAD; ++r) {
                float rv = rbf_s[e][r];
                zx += rv * wr[r].x;
                zy += rv * wr[r].y;
            }
            unsigned int pk = (unsigned int)f2bf(swishf(zx)) |
                              ((unsigned int)f2bf(swishf(zy)) << 16);
            unsigned int byte = (unsigned int)(e * 256 + h0 * 2) ^ ((e & 7) << 4);
            *(unsigned int*)((char*)p_s + byte) = pk;
        }
    }
    __syncthreads();

    // phase 2: P-fragments from LDS (swizzled ds_read_b128); lane l&15 <-> edge row
    bf16x8 pfrag[4];
    {
        int rloc = wv * 16 + (l & 15);
        unsigned int base = (unsigned int)(rloc * 256 + (l >> 4) * 16);
        unsigned int swz = (unsigned int)((rloc & 7) << 4);
        #pragma unroll
        for (int kt = 0; kt < 4; ++kt)
            pfrag[kt] = *(const bf16x8*)((const char*)p_s + ((base + kt * 64) ^ swz));
    }

    int e_loc = wv * 16 + (l & 15);
    int ge = e0 + e_loc;
    size_t ia = (size_t)i_s[e_loc] * HIDDEN;
    size_t ja = (size_t)j_s[e_loc] * HIDDEN;
    int hq = (l >> 4) * 4;

    #pragma unroll
    for (int n = 0; n < 8; ++n) {
        f32x4 acc = {0.f, 0.f, 0.f, 0.f};
        #pragma unroll
        for (int kt = 0; kt < 4; ++kt) {
            bf16x8 wfr = *(const bf16x8*)(w5f + ((size_t)(n * 4 + kt) * 64 + l) * 8);
            acc = __builtin_amdgcn_mfma_f32_16x16x32_bf16(wfr, pfrag[kt], acc, 0, 0, 0);
        }
        if (ge < n_edges) {
            int h = n * 16 + hq;
            float4 bb = *(const float4*)(b + h);
            bf16x4 av = *(const bf16x4*)(Abf + ia + h);
            bf16x4 bv = *(const bf16x4*)(Bbf + ja + h);
            float4 o;
            o.x = swishf(acc[0] + bf2f((unsigned short)av[0]) + bf2f((unsigned short)bv[0]) + bb.x);
            o.y = swishf(acc[1] + bf2f((unsigned short)av[1]) + bf2f((unsigned short)bv[1]) + bb.y);
            o.z = swishf(acc[2] + bf2f((unsigned short)av[2]) + bf2f((unsigned short)bv[2]) + bb.z);
            o.w = swishf(acc[3] + bf2f((unsigned short)av[3]) + bf2f((unsigned short)bv[3]) + bb.w);
            *(float4*)(out + (size_t)ge * HIDDEN + h) = o;
        }
    }
}

extern "C" void kernel_launch(void* const* d_in, const int* in_sizes, int n_in,
                              void* d_out, int out_size, void* d_ws, size_t ws_size,
                              hipStream_t stream) {
    const int*   x     = (const int*)d_in[0];
    const float* chi   = (const float*)d_in[1];
    const float* rbf   = (const float*)d_in[2];
    const int*   ei    = (const int*)d_in[3];
    const int*   ej    = (const int*)d_in[4];
    const float* emb   = (const float*)d_in[5];
    const float* W_rbf = (const float*)d_in[6];
    const float* b_rbf = (const float*)d_in[7];
    const float* W     = (const float*)d_in[8];
    const float* bvec  = (const float*)d_in[9];
    float* out = (float*)d_out;

    int n_nodes = in_sizes[0];
    int n_edges = in_sizes[3];
    int vocab   = in_sizes[5] / HIDDEN;

    // workspace layout
    short* Abf = (short*)d_ws;                                   // n_nodes*128 bf16
    short* Bbf = Abf + (size_t)n_nodes * HIDDEN;                 // n_nodes*128 bf16
    float* T1  = (float*)(Bbf + (size_t)n_nodes * HIDDEN);       // vocab*128 f32
    float* T3  = T1 + (size_t)vocab * HIDDEN;
    short* wf  = (short*)(T3 + (size_t)vocab * HIDDEN);          // 3 x 16384 bf16 frags
    short* w2f = wf;
    short* w4f = wf + 16384;
    short* w5f = wf + 32768;

    k_emb_proj<<<vocab, HIDDEN, 0, stream>>>(emb, W, T1, T3, out + (out_size - 1));
    k_wprep<<<24, 256, 0, stream>>>(W, wf);
    k_node<<<(n_nodes + NB - 1) / NB, 256, 0, stream>>>(x, chi, w2f, w4f, T1, T3,
                                                        Abf, Bbf, n_nodes);
    k_edge<<<(n_edges + EB - 1) / EB, 256, 0, stream>>>(rbf, ei, ej, W_rbf, b_rbf, bvec,
                                                        w5f, Abf, Bbf, out, n_edges);
}

// Round 4
// 284.617 us; speedup vs baseline: 2.7108x; 1.2616x over previous
//
#include <hip/hip_runtime.h>
#include <hip/hip_bf16.h>

#define HIDDEN 128
#define NRAD 6

typedef short bf16x8 __attribute__((ext_vector_type(8)));
typedef short bf16x4 __attribute__((ext_vector_type(4)));
typedef float f32x4 __attribute__((ext_vector_type(4)));

__device__ __forceinline__ float swishf(float z) {
    return z / (1.0f + __expf(-z));
}

__device__ __forceinline__ unsigned short f2bf(float f) {
    unsigned int u = __float_as_uint(f);
    unsigned int r = (u + 0x7FFFu + ((u >> 16) & 1u)) >> 16;
    return (unsigned short)r;
}

__device__ __forceinline__ float bf2f(unsigned short s) {
    return __uint_as_float(((unsigned int)s) << 16);
}

__device__ __forceinline__ unsigned int pk2bf(float x, float y) {
    __hip_bfloat162 h = __float22bfloat162_rn(make_float2(x, y));
    return *reinterpret_cast<unsigned int*>(&h);
}

// ---------------------------------------------------------------------------
// Kernel 1: T1 = emb_table @ W1, T3 = emb_table @ W3  (95x128 each, tiny)
// ---------------------------------------------------------------------------
__global__ void k_emb_proj(const float* __restrict__ emb, const float* __restrict__ W,
                           float* __restrict__ T1, float* __restrict__ T3,
                           float* __restrict__ out_scalar) {
    int v = blockIdx.x;
    int h = threadIdx.x;
    if (v == 0 && h == 0) *out_scalar = 1.0f;
    const float* er = emb + v * HIDDEN;
    float a1 = 0.f, a3 = 0.f;
    #pragma unroll 4
    for (int k = 0; k < HIDDEN; ++k) {
        float e = er[k];
        a1 += e * W[k * HIDDEN + h];
        a3 += e * W[(256 + k) * HIDDEN + h];
    }
    T1[v * HIDDEN + h] = a1;
    T3[v * HIDDEN + h] = a3;
}

// ---------------------------------------------------------------------------
// Kernel 1b: repack W2, W4, W5 into bf16 MFMA A-operand fragments of W^T.
// ---------------------------------------------------------------------------
__global__ void k_wprep(const float* __restrict__ W, short* __restrict__ wf) {
    int gid = blockIdx.x * 256 + threadIdx.x;   // 0..6143
    int m = gid >> 11;
    int t = gid & 2047;
    int l = t & 63;
    int tile = t >> 6;
    int n = tile >> 2, kt = tile & 3;
    int k0 = kt * 32 + (l >> 4) * 8;
    int col = n * 16 + (l & 15);
    static const int rowoff[3] = {128, 384, 512};   // W2, W4, W5
    const float* Wm = W + rowoff[m] * HIDDEN;
    bf16x8 v;
    #pragma unroll
    for (int j = 0; j < 8; ++j) v[j] = (short)f2bf(Wm[(k0 + j) * HIDDEN + col]);
    *(bf16x8*)(wf + (size_t)gid * 8) = v;
}

// ---------------------------------------------------------------------------
// Kernel 2 (MFMA): A[n] = T1[x[n]] + chi[n]@W2 ; B[n] = T3[x[n]] + chi[n]@W4
// ---------------------------------------------------------------------------
#define NB 64
__global__ __launch_bounds__(256) void k_node(const int* __restrict__ x,
        const float* __restrict__ chi,
        const short* __restrict__ w2f, const short* __restrict__ w4f,
        const float* __restrict__ T1, const float* __restrict__ T3,
        short* __restrict__ Abf, short* __restrict__ Bbf, int n_nodes) {
    __shared__ unsigned short chi_s[NB * HIDDEN];   // 16 KB bf16, row-swizzled
    __shared__ int x_s[NB];
    int n0 = blockIdx.x * NB;
    int t = threadIdx.x;
    int l = t & 63;
    int wv = t >> 6;

    #pragma unroll
    for (int it = 0; it < 8; ++it) {
        int q = t + it * 256;
        int row = q >> 5, s = q & 31;
        int gn = n0 + row;
        float4 c = (gn < n_nodes) ? *(const float4*)(chi + (size_t)gn * HIDDEN + s * 4)
                                  : make_float4(0.f, 0.f, 0.f, 0.f);
        unsigned int lo = pk2bf(c.x, c.y), hi = pk2bf(c.z, c.w);
        unsigned int byte = (unsigned int)(row * 256 + s * 8) ^ ((row & 7) << 4);
        *(uint2*)((char*)chi_s + byte) = make_uint2(lo, hi);
    }
    if (t < NB) {
        int gn = n0 + t;
        x_s[t] = (gn < n_nodes) ? x[gn] : 0;
    }
    __syncthreads();

    bf16x8 cfrag[4];
    {
        int rloc = wv * 16 + (l & 15);
        unsigned int base = (unsigned int)(rloc * 256 + (l >> 4) * 16);
        unsigned int swz = (unsigned int)((rloc & 7) << 4);
        #pragma unroll
        for (int kt = 0; kt < 4; ++kt)
            cfrag[kt] = *(const bf16x8*)((const char*)chi_s + ((base + kt * 64) ^ swz));
    }

    int nd_loc = wv * 16 + (l & 15);
    int gn = n0 + nd_loc;
    int xv = x_s[nd_loc];
    int hq = (l >> 4) * 4;

    #pragma unroll
    for (int n = 0; n < 8; ++n) {
        f32x4 aA = {0.f, 0.f, 0.f, 0.f};
        f32x4 aB = {0.f, 0.f, 0.f, 0.f};
        #pragma unroll
        for (int kt = 0; kt < 4; ++kt) {
            bf16x8 w2 = *(const bf16x8*)(w2f + ((size_t)(n * 4 + kt) * 64 + l) * 8);
            bf16x8 w4 = *(const bf16x8*)(w4f + ((size_t)(n * 4 + kt) * 64 + l) * 8);
            aA = __builtin_amdgcn_mfma_f32_16x16x32_bf16(w2, cfrag[kt], aA, 0, 0, 0);
            aB = __builtin_amdgcn_mfma_f32_16x16x32_bf16(w4, cfrag[kt], aB, 0, 0, 0);
        }
        if (gn < n_nodes) {
            int h = n * 16 + hq;
            float4 t1 = *(const float4*)(T1 + (size_t)xv * HIDDEN + h);
            float4 t3 = *(const float4*)(T3 + (size_t)xv * HIDDEN + h);
            unsigned int a0 = pk2bf(aA[0] + t1.x, aA[1] + t1.y);
            unsigned int a1 = pk2bf(aA[2] + t1.z, aA[3] + t1.w);
            unsigned int b0 = pk2bf(aB[0] + t3.x, aB[1] + t3.y);
            unsigned int b1 = pk2bf(aB[2] + t3.z, aB[3] + t3.w);
            *(uint2*)(Abf + (size_t)gn * HIDDEN + h) = make_uint2(a0, a1);
            *(uint2*)(Bbf + (size_t)gn * HIDDEN + h) = make_uint2(b0, b1);
        }
    }
}

// ---------------------------------------------------------------------------
// Kernel 3 (MFMA): out[e] = swish(A[i] + B[j] + swish(rbf@W_rbf+b_rbf)@W5 + b)
// Gathers prefetched before phase-1; epilogue LDS-transposed for full-line
// nontemporal stores.
// ---------------------------------------------------------------------------
#define EB 64
__global__ __launch_bounds__(256) void k_edge(const float* __restrict__ rbf,
        const int* __restrict__ ei, const int* __restrict__ ej,
        const float* __restrict__ W_rbf, const float* __restrict__ b_rbf,
        const float* __restrict__ b,
        const short* __restrict__ w5f,
        const short* __restrict__ Abf, const short* __restrict__ Bbf,
        float* __restrict__ out, int n_edges) {
    __shared__ unsigned short p_s[EB * HIDDEN];   // 16 KB; reused as f32 seg tiles
    __shared__ float rbf_s[EB][NRAD];
    __shared__ int i_s[EB], j_s[EB];
    int e0 = blockIdx.x * EB;
    int t = threadIdx.x;
    int l = t & 63;
    int wv = t >> 6;

    for (int q = t; q < EB * NRAD; q += 256) {
        int g = e0 * NRAD + q;
        ((float*)rbf_s)[q] = (g < n_edges * NRAD) ? rbf[g] : 0.f;
    }
    if (t < EB) {
        int ge = e0 + t;
        i_s[t] = (ge < n_edges) ? ei[ge] : 0;
        j_s[t] = (ge < n_edges) ? ej[ge] : 0;
    }
    __syncthreads();

    // prefetch A/B gathers (issue early; consumed after MFMA)
    int e_loc = wv * 16 + (l & 15);
    int hq = (l >> 4) * 4;
    const short* aptr = Abf + (size_t)i_s[e_loc] * HIDDEN + hq;
    const short* bptr = Bbf + (size_t)j_s[e_loc] * HIDDEN + hq;
    bf16x4 av[8], bv[8];
    #pragma unroll
    for (int n = 0; n < 8; ++n) {
        av[n] = *(const bf16x4*)(aptr + n * 16);
        bv[n] = *(const bf16x4*)(bptr + n * 16);
    }

    // phase 1: p = swish(rbf @ W_rbf + b_rbf) -> bf16 into swizzled LDS
    {
        int h0 = l * 2;
        float2 wr[NRAD];
        #pragma unroll
        for (int r = 0; r < NRAD; ++r) wr[r] = *(const float2*)(W_rbf + r * HIDDEN + h0);
        float2 bb = *(const float2*)(b_rbf + h0);
        #pragma unroll
        for (int m = 0; m < 16; ++m) {
            int e = wv + 4 * m;
            float zx = bb.x, zy = bb.y;
            #pragma unroll
            for (int r = 0; r < NRAD; ++r) {
                float rv = rbf_s[e][r];
                zx += rv * wr[r].x;
                zy += rv * wr[r].y;
            }
            unsigned int pk = pk2bf(swishf(zx), swishf(zy));
            unsigned int byte = (unsigned int)(e * 256 + h0 * 2) ^ ((e & 7) << 4);
            *(unsigned int*)((char*)p_s + byte) = pk;
        }
    }
    __syncthreads();

    // P-fragments from LDS (each wave reads only its own 16 rows)
    bf16x8 pfrag[4];
    {
        int rloc = wv * 16 + (l & 15);
        unsigned int base = (unsigned int)(rloc * 256 + (l >> 4) * 16);
        unsigned int swz = (unsigned int)((rloc & 7) << 4);
        #pragma unroll
        for (int kt = 0; kt < 4; ++kt)
            pfrag[kt] = *(const bf16x8*)((const char*)p_s + ((base + kt * 64) ^ swz));
    }
    __syncthreads();   // all pfrag reads done before p_s reuse below

    // MFMA: acc[n] covers h = n*16+hq..+3 for edge e_loc
    f32x4 acc[8];
    #pragma unroll
    for (int n = 0; n < 8; ++n) {
        f32x4 a = {0.f, 0.f, 0.f, 0.f};
        #pragma unroll
        for (int kt = 0; kt < 4; ++kt) {
            bf16x8 wfr = *(const bf16x8*)(w5f + ((size_t)(n * 4 + kt) * 64 + l) * 8);
            a = __builtin_amdgcn_mfma_f32_16x16x32_bf16(wfr, pfrag[kt], a, 0, 0, 0);
        }
        acc[n] = a;
    }

    char* seg = (char*)p_s + wv * 4096;   // this wave's 4 KB slice (its pfrag rows)
    if (e0 + EB <= n_edges) {
        #pragma unroll
        for (int sgi = 0; sgi < 2; ++sgi) {
            // write final f32 values, transposed-swizzled, into wave-local LDS
            #pragma unroll
            for (int nn = 0; nn < 4; ++nn) {
                int n = sgi * 4 + nn;
                float4 bb = *(const float4*)(b + n * 16 + hq);
                f32x4 o;
                o[0] = swishf(acc[n][0] + bf2f((unsigned short)av[n][0]) + bf2f((unsigned short)bv[n][0]) + bb.x);
                o[1] = swishf(acc[n][1] + bf2f((unsigned short)av[n][1]) + bf2f((unsigned short)bv[n][1]) + bb.y);
                o[2] = swishf(acc[n][2] + bf2f((unsigned short)av[n][2]) + bf2f((unsigned short)bv[n][2]) + bb.z);
                o[3] = swishf(acc[n][3] + bf2f((unsigned short)av[n][3]) + bf2f((unsigned short)bv[n][3]) + bb.w);
                int e = l & 15;
                unsigned int byte = (unsigned int)(e * 256 + (nn * 16 + hq) * 4) ^ ((e & 7) << 4);
                *(f32x4*)(seg + byte) = o;
            }
            // read back row-major, store full 128-B lines (8 edges x 128 B per instr)
            #pragma unroll
            for (int eh = 0; eh < 2; ++eh) {
                #pragma unroll
                for (int r = 0; r < 2; ++r) {
                    int e = eh * 8 + (l >> 3);
                    int coff = (l & 7) * 16 + r * 128;   // byte within 256-B seg row
                    unsigned int byte = (unsigned int)(e * 256 + coff) ^ ((e & 7) << 4);
                    f32x4 v = *(const f32x4*)(seg + byte);
                    float* dst = out + (size_t)(e0 + wv * 16 + e) * HIDDEN + sgi * 64 + coff / 4;
                    __builtin_nontemporal_store(v, (f32x4*)dst);
                }
            }
        }
    } else {
        // tail fallback: direct guarded stores
        int ge = e0 + e_loc;
        #pragma unroll
        for (int n = 0; n < 8; ++n) {
            if (ge < n_edges) {
                int h = n * 16 + hq;
                float4 bb = *(const float4*)(b + h);
                float4 o;
                o.x = swishf(acc[n][0] + bf2f((unsigned short)av[n][0]) + bf2f((unsigned short)bv[n][0]) + bb.x);
                o.y = swishf(acc[n][1] + bf2f((unsigned short)av[n][1]) + bf2f((unsigned short)bv[n][1]) + bb.y);
                o.z = swishf(acc[n][2] + bf2f((unsigned short)av[n][2]) + bf2f((unsigned short)bv[n][2]) + bb.z);
                o.w = swishf(acc[n][3] + bf2f((unsigned short)av[n][3]) + bf2f((unsigned short)bv[n][3]) + bb.w);
                *(float4*)(out + (size_t)ge * HIDDEN + h) = o;
            }
        }
    }
}

extern "C" void kernel_launch(void* const* d_in, const int* in_sizes, int n_in,
                              void* d_out, int out_size, void* d_ws, size_t ws_size,
                              hipStream_t stream) {
    const int*   x     = (const int*)d_in[0];
    const float* chi   = (const float*)d_in[1];
    const float* rbf   = (const float*)d_in[2];
    const int*   ei    = (const int*)d_in[3];
    const int*   ej    = (const int*)d_in[4];
    const float* emb   = (const float*)d_in[5];
    const float* W_rbf = (const float*)d_in[6];
    const float* b_rbf = (const float*)d_in[7];
    const float* W     = (const float*)d_in[8];
    const float* bvec  = (const float*)d_in[9];
    float* out = (float*)d_out;

    int n_nodes = in_sizes[0];
    int n_edges = in_sizes[3];
    int vocab   = in_sizes[5] / HIDDEN;

    short* Abf = (short*)d_ws;
    short* Bbf = Abf + (size_t)n_nodes * HIDDEN;
    float* T1  = (float*)(Bbf + (size_t)n_nodes * HIDDEN);
    float* T3  = T1 + (size_t)vocab * HIDDEN;
    short* wf  = (short*)(T3 + (size_t)vocab * HIDDEN);
    short* w2f = wf;
    short* w4f = wf + 16384;
    short* w5f = wf + 32768;

    k_emb_proj<<<vocab, HIDDEN, 0, stream>>>(emb, W, T1, T3, out + (out_size - 1));
    k_wprep<<<24, 256, 0, stream>>>(W, wf);
    k_node<<<(n_nodes + NB - 1) / NB, 256, 0, stream>>>(x, chi, w2f, w4f, T1, T3,
                                                        Abf, Bbf, n_nodes);
    k_edge<<<(n_edges + EB - 1) / EB, 256, 0, stream>>>(rbf, ei, ej, W_rbf, b_rbf, bvec,
                                                        w5f, Abf, Bbf, out, n_edges);
}